// Round 1
// baseline (113.087 us; speedup 1.0000x reference)
//
#include <hip/hip_runtime.h>
#include <math.h>

// RelativeGeoSymLoss: B=8, N=4096 symmetric chamfer + trans L1.
// v2: single fused pass over unique pairs (both row-min and col-min from one
// distance evaluation), atomic-free combine via partial-min arrays.
// ws layout (bytes):
//   0                 : pts  [2][B][N] float4 (x,y,z,||.||^2)           1 MB
//   2*B*N*16          : rowp [nMC][B*N] float  (row-min partials, dist^2) 8 MB
//   + nMC*B*N*4       : colp [nRC][B*N] float  (col-min partials, dist^2) 256 KB

#define TPB 256
#define RPT 8            // rows per thread
#define MC  64           // gt-point chunk staged in LDS (1 KB)
#define RC  (TPB * RPT)  // rows per block = 2048

// rel_rot = Ra @ Rb^T ; rel_trans = ta - rel_rot @ tb
__device__ __forceinline__ void rel_tf(const float* __restrict__ Ra,
                                       const float* __restrict__ ta,
                                       const float* __restrict__ Rb,
                                       const float* __restrict__ tb,
                                       float* R, float* t) {
#pragma unroll
    for (int i = 0; i < 3; i++)
#pragma unroll
        for (int k = 0; k < 3; k++)
            R[i * 3 + k] = Ra[i * 3 + 0] * Rb[k * 3 + 0]
                         + Ra[i * 3 + 1] * Rb[k * 3 + 1]
                         + Ra[i * 3 + 2] * Rb[k * 3 + 2];
#pragma unroll
    for (int i = 0; i < 3; i++)
        t[i] = ta[i] - (R[i * 3 + 0] * tb[0] + R[i * 3 + 1] * tb[1]
                      + R[i * 3 + 2] * tb[2]);
}

// Transforms + point transform + out init (out[0]=0, out[1]=trans L1 loss).
__global__ void k_prep(const float* __restrict__ pred_rot,
                       const float* __restrict__ pred_trans,
                       const float* __restrict__ ctx_hyp_rot,
                       const float* __restrict__ ctx_hyp_trans,
                       const float* __restrict__ gt_rot,
                       const float* __restrict__ gt_trans,
                       const float* __restrict__ ctx_gt_rot,
                       const float* __restrict__ ctx_gt_trans,
                       const float* __restrict__ mp,
                       float4* __restrict__ pts,
                       float* __restrict__ out, int B, int N) {
    int idx = blockIdx.x * blockDim.x + threadIdx.x;
    if (idx >= B * N) return;
    int b = idx / N;
    float px = mp[idx * 3 + 0], py = mp[idx * 3 + 1], pz = mp[idx * 3 + 2];
    float R[9], t[3];
#pragma unroll
    for (int g = 0; g < 2; g++) {
        if (g == 0)
            rel_tf(pred_rot + b * 9, pred_trans + b * 3,
                   ctx_hyp_rot + b * 9, ctx_hyp_trans + b * 3, R, t);
        else
            rel_tf(gt_rot + b * 9, gt_trans + b * 3,
                   ctx_gt_rot + b * 9, ctx_gt_trans + b * 3, R, t);
        float x = R[0] * px + R[1] * py + R[2] * pz + t[0];
        float y = R[3] * px + R[4] * py + R[5] * pz + t[1];
        float z = R[6] * px + R[7] * py + R[8] * pz + t[2];
        pts[(size_t)g * B * N + idx] = make_float4(x, y, z, x * x + y * y + z * z);
    }
    if (idx == 0) {
        out[0] = 0.0f;
        float lt = 0.0f;
        for (int bb = 0; bb < B; bb++) {
            float Rp[9], tp[3], Rg[9], tg[3];
            rel_tf(pred_rot + bb * 9, pred_trans + bb * 3,
                   ctx_hyp_rot + bb * 9, ctx_hyp_trans + bb * 3, Rp, tp);
            rel_tf(gt_rot + bb * 9, gt_trans + bb * 3,
                   ctx_gt_rot + bb * 9, ctx_gt_trans + bb * 3, Rg, tg);
            lt += fabsf(tp[0] - tg[0]) + fabsf(tp[1] - tg[1]) + fabsf(tp[2] - tg[2]);
        }
        out[1] = lt / (float)(3 * B);
    }
}

// Fused chamfer: each block = RC pred-rows x one MC-chunk of gt points.
// Row-min kept in registers (dist^2, ||a||^2 folded). Col-min: lane-local min
// over RPT rows, 6-step shfl_xor wave reduce, per-wave LDS slot, block combine.
// All partial results stored with plain coalesced writes (no atomics).
__global__ void __launch_bounds__(TPB, 4)
k_fused(const float4* __restrict__ pts,
        float* __restrict__ rowp, float* __restrict__ colp, int B, int N) {
    int nMC = N / MC;
    int b  = blockIdx.y;
    int rc = blockIdx.x / nMC;
    int mc = blockIdx.x % nMC;
    size_t BN = (size_t)B * N;
    const float4* Ap = pts + (size_t)b * N;        // pred points
    const float4* Gp = pts + BN + (size_t)b * N;   // gt points

    __shared__ float4 sG[MC];
    __shared__ float cmw[TPB / 64][MC];            // per-wave col-min partials
    int tid = threadIdx.x;
    if (tid < MC) sG[tid] = Gp[mc * MC + tid];

    int rowBase = rc * RC;
    float a2x[RPT], a2y[RPT], a2z[RPT], aw[RPT], mn[RPT];
#pragma unroll
    for (int r = 0; r < RPT; r++) {
        float4 a = Ap[rowBase + tid + TPB * r];
        a2x[r] = -2.0f * a.x;
        a2y[r] = -2.0f * a.y;
        a2z[r] = -2.0f * a.z;
        aw[r]  = a.w;
        mn[r]  = INFINITY;
    }
    __syncthreads();

    int wid = tid >> 6, lane = tid & 63;
#pragma unroll 2
    for (int m = 0; m < MC; m += 2) {
        float4 g0 = sG[m];       // wave-uniform -> LDS broadcast
        float4 g1 = sG[m + 1];
        float c0, c1;
#pragma unroll
        for (int r = 0; r < RPT; r++) {
            float p0 = __builtin_fmaf(a2z[r], g0.z, g0.w);
            p0 = __builtin_fmaf(a2y[r], g0.y, p0);
            p0 = __builtin_fmaf(a2x[r], g0.x, p0);
            float p1 = __builtin_fmaf(a2z[r], g1.z, g1.w);
            p1 = __builtin_fmaf(a2y[r], g1.y, p1);
            p1 = __builtin_fmaf(a2x[r], g1.x, p1);
            float d0 = p0 + aw[r];                 // full dist^2
            float d1 = p1 + aw[r];
            mn[r] = fminf(fminf(mn[r], d0), d1);   // -> v_min3
            c0 = (r == 0) ? d0 : fminf(c0, d0);
            c1 = (r == 0) ? d1 : fminf(c1, d1);
        }
        // wave-wide min of c0,c1 (results only feed an LDS store; the
        // compiler can overlap this chain with the next iteration's FMAs)
#pragma unroll
        for (int off = 1; off < 64; off <<= 1) {
            c0 = fminf(c0, __shfl_xor(c0, off, 64));
            c1 = fminf(c1, __shfl_xor(c1, off, 64));
        }
        if (lane == 0) { cmw[wid][m] = c0; cmw[wid][m + 1] = c1; }
    }

    // row-min partials: plain coalesced stores
    float* rp = rowp + (size_t)mc * BN + (size_t)b * N + rowBase + tid;
#pragma unroll
    for (int r = 0; r < RPT; r++) rp[(size_t)TPB * r] = mn[r];

    __syncthreads();
    if (tid < MC) {
        float c = fminf(fminf(cmw[0][tid], cmw[1][tid]),
                        fminf(cmw[2][tid], cmw[3][tid]));
        colp[(size_t)rc * BN + (size_t)b * N + mc * MC + tid] = c;
    }
}

__global__ void __launch_bounds__(TPB)
k_finalize(const float* __restrict__ rowp, const float* __restrict__ colp,
           float* __restrict__ out, int B, int N, int nMC, int nRC) {
    size_t BN = (size_t)B * N;
    int total = 2 * (int)BN;
    float s = 0.0f;
    for (int i = blockIdx.x * blockDim.x + threadIdx.x; i < total;
         i += gridDim.x * blockDim.x) {
        const float* src;
        int cnt;
        size_t off;
        if (i < (int)BN) { src = rowp; cnt = nMC; off = (size_t)i; }
        else             { src = colp; cnt = nRC; off = (size_t)i - BN; }
        float m0 = src[off];
        float m1 = src[BN + off];
        for (int k = 2; k + 1 < cnt; k += 2) {
            m0 = fminf(m0, src[(size_t)k * BN + off]);
            m1 = fminf(m1, src[(size_t)(k + 1) * BN + off]);
        }
        float m = fminf(m0, m1);
        s += sqrtf(fmaxf(m, 0.0f));
    }
#pragma unroll
    for (int off = 32; off > 0; off >>= 1) s += __shfl_down(s, off, 64);
    __shared__ float red[TPB / 64];
    int wid = threadIdx.x >> 6, lane = threadIdx.x & 63;
    if (lane == 0) red[wid] = s;
    __syncthreads();
    if (threadIdx.x == 0) {
        float t = 0.0f;
#pragma unroll
        for (int w = 0; w < TPB / 64; w++) t += red[w];
        atomicAdd(&out[0], t / (float)(B * N));
    }
}

extern "C" void kernel_launch(void* const* d_in, const int* in_sizes, int n_in,
                              void* d_out, int out_size, void* d_ws, size_t ws_size,
                              hipStream_t stream) {
    const float* pred_rot      = (const float*)d_in[0];
    const float* pred_trans    = (const float*)d_in[1];
    const float* ctx_hyp_rot   = (const float*)d_in[2];
    const float* ctx_hyp_trans = (const float*)d_in[3];
    const float* gt_rot        = (const float*)d_in[4];
    const float* gt_trans      = (const float*)d_in[5];
    const float* ctx_gt_rot    = (const float*)d_in[6];
    const float* ctx_gt_trans  = (const float*)d_in[7];
    const float* model_points  = (const float*)d_in[8];

    int B = in_sizes[0] / 9;
    int N = in_sizes[8] / (3 * B);
    size_t BN = (size_t)B * N;
    int nMC = N / MC;
    int nRC = N / RC;

    char* ws = (char*)d_ws;
    float4* pts  = (float4*)ws;
    float*  rowp = (float*)(ws + 2 * BN * sizeof(float4));
    float*  colp = rowp + (size_t)nMC * BN;
    float*  out  = (float*)d_out;

    k_prep<<<(B * N + TPB - 1) / TPB, TPB, 0, stream>>>(
        pred_rot, pred_trans, ctx_hyp_rot, ctx_hyp_trans,
        gt_rot, gt_trans, ctx_gt_rot, ctx_gt_trans,
        model_points, pts, out, B, N);

    dim3 grid(nRC * nMC, B);  // (2*64, 8) = 1024 blocks, 4 blocks/CU
    k_fused<<<grid, TPB, 0, stream>>>(pts, rowp, colp, B, N);

    k_finalize<<<128, TPB, 0, stream>>>(rowp, colp, out, B, N, nMC, nRC);
}

// Round 2
// 106.105 us; speedup vs baseline: 1.0658x; 1.0658x over previous
//
#include <hip/hip_runtime.h>
#include <math.h>

// RelativeGeoSymLoss: B=8, N=4096 symmetric chamfer + trans L1.
// v3: v1's two-dir register-min structure + packed-FP32 inner loop
// (v_pk_fma_f32, 2 columns/inst) + atomic-free partial-min combine.
// ws layout (bytes):
//   0        : pts  [2][B][N] float4 (x,y,z,||.||^2)                  1 MB
//   2*B*N*16 : rowp [nMC][2*B*N] float (row-min partials, -2a.g+|g|^2)  8 MB

#define TPB 256
#define RPT 8            // rows per thread
#define MC  128          // gt-point chunk staged in LDS (SoA, 2 KB)
#define RC  (TPB * RPT)  // rows per block = 2048

typedef float f32x2 __attribute__((ext_vector_type(2)));

__device__ __forceinline__ f32x2 pk_fma(f32x2 a, f32x2 b, f32x2 c) {
    f32x2 d;
    asm("v_pk_fma_f32 %0, %1, %2, %3" : "=v"(d) : "v"(a), "v"(b), "v"(c));
    return d;
}
__device__ __forceinline__ float min3f(float a, float b, float c) {
    float d;
    asm("v_min3_f32 %0, %1, %2, %3" : "=v"(d) : "v"(a), "v"(b), "v"(c));
    return d;
}

// rel_rot = Ra @ Rb^T ; rel_trans = ta - rel_rot @ tb
__device__ __forceinline__ void rel_tf(const float* __restrict__ Ra,
                                       const float* __restrict__ ta,
                                       const float* __restrict__ Rb,
                                       const float* __restrict__ tb,
                                       float* R, float* t) {
#pragma unroll
    for (int i = 0; i < 3; i++)
#pragma unroll
        for (int k = 0; k < 3; k++)
            R[i * 3 + k] = Ra[i * 3 + 0] * Rb[k * 3 + 0]
                         + Ra[i * 3 + 1] * Rb[k * 3 + 1]
                         + Ra[i * 3 + 2] * Rb[k * 3 + 2];
#pragma unroll
    for (int i = 0; i < 3; i++)
        t[i] = ta[i] - (R[i * 3 + 0] * tb[0] + R[i * 3 + 1] * tb[1]
                      + R[i * 3 + 2] * tb[2]);
}

// Transforms + point transform + out init (out[0]=0, out[1]=trans L1 loss).
__global__ void k_prep(const float* __restrict__ pred_rot,
                       const float* __restrict__ pred_trans,
                       const float* __restrict__ ctx_hyp_rot,
                       const float* __restrict__ ctx_hyp_trans,
                       const float* __restrict__ gt_rot,
                       const float* __restrict__ gt_trans,
                       const float* __restrict__ ctx_gt_rot,
                       const float* __restrict__ ctx_gt_trans,
                       const float* __restrict__ mp,
                       float4* __restrict__ pts,
                       float* __restrict__ out, int B, int N) {
    int idx = blockIdx.x * blockDim.x + threadIdx.x;
    if (idx >= B * N) return;
    int b = idx / N;
    float px = mp[idx * 3 + 0], py = mp[idx * 3 + 1], pz = mp[idx * 3 + 2];
    float R[9], t[3];
#pragma unroll
    for (int g = 0; g < 2; g++) {
        if (g == 0)
            rel_tf(pred_rot + b * 9, pred_trans + b * 3,
                   ctx_hyp_rot + b * 9, ctx_hyp_trans + b * 3, R, t);
        else
            rel_tf(gt_rot + b * 9, gt_trans + b * 3,
                   ctx_gt_rot + b * 9, ctx_gt_trans + b * 3, R, t);
        float x = R[0] * px + R[1] * py + R[2] * pz + t[0];
        float y = R[3] * px + R[4] * py + R[5] * pz + t[1];
        float z = R[6] * px + R[7] * py + R[8] * pz + t[2];
        pts[(size_t)g * B * N + idx] = make_float4(x, y, z, x * x + y * y + z * z);
    }
    if (idx == 0) {
        out[0] = 0.0f;
        float lt = 0.0f;
        for (int bb = 0; bb < B; bb++) {
            float Rp[9], tp[3], Rg[9], tg[3];
            rel_tf(pred_rot + bb * 9, pred_trans + bb * 3,
                   ctx_hyp_rot + bb * 9, ctx_hyp_trans + bb * 3, Rp, tp);
            rel_tf(gt_rot + bb * 9, gt_trans + bb * 3,
                   ctx_gt_rot + bb * 9, ctx_gt_trans + bb * 3, Rg, tg);
            lt += fabsf(tp[0] - tg[0]) + fabsf(tp[1] - tg[1]) + fabsf(tp[2] - tg[2]);
        }
        out[1] = lt / (float)(3 * B);
    }
}

// Each block: RC rows of dir's points x one MC-chunk of the other set.
// gt chunk staged in LDS as SoA, pre-scaled by -2 (x,y,z) with |g|^2 seed.
// Inner: 2 columns per v_pk_fma_f32 triple + one v_min3_f32 -> 2 inst/pair.
// Row-min (excl |a|^2) kept in registers; plain coalesced partial stores.
__global__ void __launch_bounds__(TPB, 4)
k_chamfer(const float4* __restrict__ pts, float* __restrict__ rowp,
          int B, int N) {
    int dir = blockIdx.z;
    int b = blockIdx.y;
    int nMC = N / MC;
    int rc = blockIdx.x / nMC;
    int mc = blockIdx.x % nMC;
    size_t BN = (size_t)B * N;
    const float4* Ap = pts + ((size_t)dir * B + b) * N;
    const float4* Gp = pts + ((size_t)(1 - dir) * B + b) * N;

    __shared__ __align__(16) float sGx[MC], sGy[MC], sGz[MC], sGw[MC];
    int tid = threadIdx.x;
    if (tid < MC) {
        float4 g = Gp[mc * MC + tid];
        sGx[tid] = -2.0f * g.x;
        sGy[tid] = -2.0f * g.y;
        sGz[tid] = -2.0f * g.z;
        sGw[tid] = g.w;
    }

    int rowBase = rc * RC;
    f32x2 ax2[RPT], ay2[RPT], az2[RPT];
    float mn[RPT];
#pragma unroll
    for (int r = 0; r < RPT; r++) {
        float4 a = Ap[rowBase + tid + TPB * r];
        ax2[r] = f32x2{a.x, a.x};
        ay2[r] = f32x2{a.y, a.y};
        az2[r] = f32x2{a.z, a.z};
        mn[r] = INFINITY;
    }
    __syncthreads();

    const f32x2* gx2 = (const f32x2*)sGx;
    const f32x2* gy2 = (const f32x2*)sGy;
    const f32x2* gz2 = (const f32x2*)sGz;
    const f32x2* gw2 = (const f32x2*)sGw;
#pragma unroll 2
    for (int m = 0; m < MC / 2; m++) {
        f32x2 gx = gx2[m], gy = gy2[m], gz = gz2[m], gw = gw2[m];
#pragma unroll
        for (int r = 0; r < RPT; r++) {
            f32x2 p = pk_fma(az2[r], gz, gw);
            p = pk_fma(ay2[r], gy, p);
            p = pk_fma(ax2[r], gx, p);
            mn[r] = min3f(mn[r], p.x, p.y);
        }
    }

    float* rp = rowp + (size_t)mc * 2 * BN
              + (size_t)dir * BN + (size_t)b * N + rowBase + tid;
#pragma unroll
    for (int r = 0; r < RPT; r++) rp[(size_t)TPB * r] = mn[r];
}

__global__ void __launch_bounds__(TPB)
k_finalize(const float4* __restrict__ pts, const float* __restrict__ rowp,
           float* __restrict__ out, int B, int N, int nMC) {
    size_t BN2 = (size_t)2 * B * N;
    float s = 0.0f;
    for (size_t i = blockIdx.x * blockDim.x + threadIdx.x; i < BN2;
         i += (size_t)gridDim.x * blockDim.x) {
        float m0 = rowp[i];
        float m1 = rowp[BN2 + i];
        for (int k = 2; k + 1 < nMC; k += 2) {
            m0 = fminf(m0, rowp[(size_t)k * BN2 + i]);
            m1 = fminf(m1, rowp[(size_t)(k + 1) * BN2 + i]);
        }
        float m = fminf(m0, m1);
        s += sqrtf(fmaxf(m + pts[i].w, 0.0f));  // + |a|^2, clamp
    }
#pragma unroll
    for (int off = 32; off > 0; off >>= 1) s += __shfl_down(s, off, 64);
    __shared__ float red[TPB / 64];
    int wid = threadIdx.x >> 6, lane = threadIdx.x & 63;
    if (lane == 0) red[wid] = s;
    __syncthreads();
    if (threadIdx.x == 0) {
        float t = 0.0f;
#pragma unroll
        for (int w = 0; w < TPB / 64; w++) t += red[w];
        atomicAdd(&out[0], t / (float)(B * N));
    }
}

extern "C" void kernel_launch(void* const* d_in, const int* in_sizes, int n_in,
                              void* d_out, int out_size, void* d_ws, size_t ws_size,
                              hipStream_t stream) {
    const float* pred_rot      = (const float*)d_in[0];
    const float* pred_trans    = (const float*)d_in[1];
    const float* ctx_hyp_rot   = (const float*)d_in[2];
    const float* ctx_hyp_trans = (const float*)d_in[3];
    const float* gt_rot        = (const float*)d_in[4];
    const float* gt_trans      = (const float*)d_in[5];
    const float* ctx_gt_rot    = (const float*)d_in[6];
    const float* ctx_gt_trans  = (const float*)d_in[7];
    const float* model_points  = (const float*)d_in[8];

    int B = in_sizes[0] / 9;
    int N = in_sizes[8] / (3 * B);
    size_t BN = (size_t)B * N;
    int nMC = N / MC;
    int nRC = N / RC;

    char* ws = (char*)d_ws;
    float4* pts  = (float4*)ws;
    float*  rowp = (float*)(ws + 2 * BN * sizeof(float4));
    float*  out  = (float*)d_out;

    k_prep<<<(B * N + TPB - 1) / TPB, TPB, 0, stream>>>(
        pred_rot, pred_trans, ctx_hyp_rot, ctx_hyp_trans,
        gt_rot, gt_trans, ctx_gt_rot, ctx_gt_trans,
        model_points, pts, out, B, N);

    dim3 grid(nRC * nMC, B, 2);  // (2*32, 8, 2) = 1024 blocks, 4 blocks/CU
    k_chamfer<<<grid, TPB, 0, stream>>>(pts, rowp, B, N);

    k_finalize<<<128, TPB, 0, stream>>>(pts, rowp, out, B, N, nMC);
}

// Round 3
// 90.899 us; speedup vs baseline: 1.2441x; 1.1673x over previous
//
#include <hip/hip_runtime.h>
#include <math.h>

// RelativeGeoSymLoss: B=8, N=4096 symmetric chamfer + trans L1.
// v4: MFMA chamfer. dist^2 = |p|^2 + |g|^2 - 2 p.g ; the -2p.g term (K=3
// matmul) + |g|^2 fold computed by ONE v_mfma_f32_32x32x16_bf16 per 32x32
// tile via fp32->bf16 hi/lo split packed into 14 of 16 K-slots.
// Two row-min passes (rows=pred / rows=gt) share precomputed fragments;
// row-mins live in registers, final cross-lane reduce + per-block atomicAdd.
// ws layout (uint4 granularity):
//   0      : Arow [2][B][T][64] uint4  (row-operand frags, -2p hi/lo)  2 MB
//   2 MB   : Bcol [2][B][T][64] uint4  (col-operand frags, g hi/lo+|g|^2) 2 MB
//   4 MB   : pw   [2][B][N] float      (|p|^2 fp32)                   256 KB
// T = N/32 tiles.

#define PTPB 256
#define CW   8      // waves per chamfer block (512 threads)

typedef __attribute__((ext_vector_type(8)))  short bf16x8;
typedef __attribute__((ext_vector_type(16))) float f32x16;

__device__ __forceinline__ unsigned short f2bf(float x) {  // RNE
    unsigned u = __float_as_uint(x);
    return (unsigned short)((u + 0x7FFFu + ((u >> 16) & 1u)) >> 16);
}
__device__ __forceinline__ float bf2f(unsigned short h) {
    return __uint_as_float(((unsigned)h) << 16);
}
__device__ __forceinline__ uint4 pack8(const unsigned short v[8]) {
    uint4 r;
    r.x = (unsigned)v[0] | ((unsigned)v[1] << 16);
    r.y = (unsigned)v[2] | ((unsigned)v[3] << 16);
    r.z = (unsigned)v[4] | ((unsigned)v[5] << 16);
    r.w = (unsigned)v[6] | ((unsigned)v[7] << 16);
    return r;
}

// rel_rot = Ra @ Rb^T ; rel_trans = ta - rel_rot @ tb
__device__ __forceinline__ void rel_tf(const float* __restrict__ Ra,
                                       const float* __restrict__ ta,
                                       const float* __restrict__ Rb,
                                       const float* __restrict__ tb,
                                       float* R, float* t) {
#pragma unroll
    for (int i = 0; i < 3; i++)
#pragma unroll
        for (int k = 0; k < 3; k++)
            R[i * 3 + k] = Ra[i * 3 + 0] * Rb[k * 3 + 0]
                         + Ra[i * 3 + 1] * Rb[k * 3 + 1]
                         + Ra[i * 3 + 2] * Rb[k * 3 + 2];
#pragma unroll
    for (int i = 0; i < 3; i++)
        t[i] = ta[i] - (R[i * 3 + 0] * tb[0] + R[i * 3 + 1] * tb[1]
                      + R[i * 3 + 2] * tb[2]);
}

// Transforms + point transform + fragment packing + out init.
__global__ void k_prep(const float* __restrict__ pred_rot,
                       const float* __restrict__ pred_trans,
                       const float* __restrict__ ctx_hyp_rot,
                       const float* __restrict__ ctx_hyp_trans,
                       const float* __restrict__ gt_rot,
                       const float* __restrict__ gt_trans,
                       const float* __restrict__ ctx_gt_rot,
                       const float* __restrict__ ctx_gt_trans,
                       const float* __restrict__ mp,
                       uint4* __restrict__ Arow, uint4* __restrict__ Bcol,
                       float* __restrict__ pw,
                       float* __restrict__ out, int B, int N) {
    int idx = blockIdx.x * blockDim.x + threadIdx.x;
    if (idx >= B * N) return;
    int b = idx / N, n = idx % N;
    int T = N >> 5;
    int tile = n >> 5, ln = n & 31;
    float px = mp[idx * 3 + 0], py = mp[idx * 3 + 1], pz = mp[idx * 3 + 2];
    const unsigned short one = 0x3F80;  // bf16 1.0
    float Rm[9], tv[3];
#pragma unroll
    for (int s = 0; s < 2; s++) {
        if (s == 0)
            rel_tf(pred_rot + b * 9, pred_trans + b * 3,
                   ctx_hyp_rot + b * 9, ctx_hyp_trans + b * 3, Rm, tv);
        else
            rel_tf(gt_rot + b * 9, gt_trans + b * 3,
                   ctx_gt_rot + b * 9, ctx_gt_trans + b * 3, Rm, tv);
        float x = Rm[0] * px + Rm[1] * py + Rm[2] * pz + tv[0];
        float y = Rm[3] * px + Rm[4] * py + Rm[5] * pz + tv[1];
        float z = Rm[6] * px + Rm[7] * py + Rm[8] * pz + tv[2];
        float w = x * x + y * y + z * z;

        // A-form: hi/lo split of -2p  (K slots: 0-2 ah, 3-5 al, 6-8 ah, 9-11 al, 12-13 one)
        float mx = -2.0f * x, my = -2.0f * y, mz = -2.0f * z;
        unsigned short ahx = f2bf(mx), ahy = f2bf(my), ahz = f2bf(mz);
        unsigned short alx = f2bf(mx - bf2f(ahx));
        unsigned short aly = f2bf(my - bf2f(ahy));
        unsigned short alz = f2bf(mz - bf2f(ahz));
        // B-form: hi/lo split of g and |g|^2 (K slots: 0-2 gh, 3-5 gh, 6-8 gl, 9-11 gl, 12 gwh, 13 gwl)
        unsigned short ghx = f2bf(x), ghy = f2bf(y), ghz = f2bf(z);
        unsigned short glx = f2bf(x - bf2f(ghx));
        unsigned short gly = f2bf(y - bf2f(ghy));
        unsigned short glz = f2bf(z - bf2f(ghz));
        unsigned short gwh = f2bf(w);
        unsigned short gwl = f2bf(w - bf2f(gwh));

        unsigned short a_lo[8] = {ahx, ahy, ahz, alx, aly, alz, ahx, ahy};
        unsigned short a_hi[8] = {ahz, alx, aly, alz, one, one, 0, 0};
        unsigned short b_lo[8] = {ghx, ghy, ghz, ghx, ghy, ghz, glx, gly};
        unsigned short b_hi[8] = {glz, glx, gly, glz, gwh, gwl, 0, 0};

        size_t base = (((size_t)s * B + b) * T + tile) * 64;
        Arow[base + ln]      = pack8(a_lo);
        Arow[base + 32 + ln] = pack8(a_hi);
        Bcol[base + ln]      = pack8(b_lo);
        Bcol[base + 32 + ln] = pack8(b_hi);
        pw[((size_t)s * B + b) * N + n] = w;
    }
    if (idx == 0) {
        out[0] = 0.0f;
        float lt = 0.0f;
        for (int bb = 0; bb < B; bb++) {
            float Rp[9], tp[3], Rg[9], tg[3];
            rel_tf(pred_rot + bb * 9, pred_trans + bb * 3,
                   ctx_hyp_rot + bb * 9, ctx_hyp_trans + bb * 3, Rp, tp);
            rel_tf(gt_rot + bb * 9, gt_trans + bb * 3,
                   ctx_gt_rot + bb * 9, ctx_gt_trans + bb * 3, Rg, tg);
            lt += fabsf(tp[0] - tg[0]) + fabsf(tp[1] - tg[1]) + fabsf(tp[2] - tg[2]);
        }
        out[1] = lt / (float)(3 * B);
    }
}

// One wave = one 32-row strip x all N cols. Block = 8 waves, staging the
// shared col-fragment stream through LDS (1 tile per wave per chunk).
// MFMA output D[n,m] = |g_m|^2 - 2 p_n . g_m ; row-min accumulates in regs.
__global__ void __launch_bounds__(CW * 64)
k_mfma(const uint4* __restrict__ Arow, const uint4* __restrict__ Bcol,
       const float* __restrict__ pw, float* __restrict__ out, int B, int N) {
    int T = N >> 5;
    int pass = blockIdx.z, b = blockIdx.y;
    int tid = threadIdx.x, wid = tid >> 6, lane = tid & 63;
    int strip = blockIdx.x * CW + wid;

    const uint4* Ap  = Arow + ((size_t)pass * B + b) * T * 64;
    const uint4* Bs  = Bcol + ((size_t)(1 - pass) * B + b) * T * 64;
    const float* pwp = pw + ((size_t)pass * B + b) * N;

    __shared__ uint4 sB[CW][64];   // 8 KB

    uint4 au = Ap[(size_t)strip * 64 + lane];
    bf16x8 af = *(bf16x8*)&au;

    f32x16 rmin;
#pragma unroll
    for (int r = 0; r < 16; r++) rmin[r] = INFINITY;
    f32x16 zc;
#pragma unroll
    for (int r = 0; r < 16; r++) zc[r] = 0.0f;

    uint4 stg = Bs[(size_t)wid * 64 + lane];
    int nchunk = T / CW;   // 16
    for (int c = 0; c < nchunk; c++) {
        __syncthreads();               // prev chunk fully consumed
        sB[wid][lane] = stg;
        if (c + 1 < nchunk)
            stg = Bs[(((size_t)(c + 1)) * CW + wid) * 64 + lane];  // prefetch
        __syncthreads();               // staged chunk visible
#pragma unroll
        for (int t = 0; t < CW; t++) {
            uint4 bu = sB[t][lane];
            bf16x8 bf = *(bf16x8*)&bu;
            f32x16 d = __builtin_amdgcn_mfma_f32_32x32x16_bf16(af, bf, zc, 0, 0, 0);
#pragma unroll
            for (int r = 0; r < 16; r++) rmin[r] = fminf(rmin[r], d[r]);
        }
    }

    // reduce over the 32 col-lanes (bits 0..4 of lane)
#pragma unroll
    for (int off = 1; off < 32; off <<= 1) {
#pragma unroll
        for (int r = 0; r < 16; r++)
            rmin[r] = fminf(rmin[r], __shfl_xor(rmin[r], off, 64));
    }

    float lsum = 0.0f;
    if ((lane & 31) == 0) {
        int h = lane >> 5;
        int rowbase = strip * 32;
#pragma unroll
        for (int r = 0; r < 16; r++) {
            int row = (r & 3) + 8 * (r >> 2) + 4 * h;  // m74/m101-verified C/D map
            float v = rmin[r] + pwp[rowbase + row];
            lsum += sqrtf(fmaxf(v, 0.0f));
        }
    }
    lsum += __shfl_down(lsum, 32, 64);

    __shared__ float red[CW];
    if (lane == 0) red[wid] = lsum;
    __syncthreads();
    if (tid == 0) {
        float tsum = 0.0f;
#pragma unroll
        for (int w = 0; w < CW; w++) tsum += red[w];
        atomicAdd(&out[0], tsum / (float)(B * N));
    }
}

extern "C" void kernel_launch(void* const* d_in, const int* in_sizes, int n_in,
                              void* d_out, int out_size, void* d_ws, size_t ws_size,
                              hipStream_t stream) {
    const float* pred_rot      = (const float*)d_in[0];
    const float* pred_trans    = (const float*)d_in[1];
    const float* ctx_hyp_rot   = (const float*)d_in[2];
    const float* ctx_hyp_trans = (const float*)d_in[3];
    const float* gt_rot        = (const float*)d_in[4];
    const float* gt_trans      = (const float*)d_in[5];
    const float* ctx_gt_rot    = (const float*)d_in[6];
    const float* ctx_gt_trans  = (const float*)d_in[7];
    const float* model_points  = (const float*)d_in[8];

    int B = in_sizes[0] / 9;
    int N = in_sizes[8] / (3 * B);
    int T = N >> 5;
    size_t fragN = (size_t)2 * B * T * 64;   // uint4 count per array

    char* ws = (char*)d_ws;
    uint4* Arow = (uint4*)ws;
    uint4* Bcol = Arow + fragN;
    float* pw   = (float*)(Bcol + fragN);
    float* out  = (float*)d_out;

    k_prep<<<(B * N + PTPB - 1) / PTPB, PTPB, 0, stream>>>(
        pred_rot, pred_trans, ctx_hyp_rot, ctx_hyp_trans,
        gt_rot, gt_trans, ctx_gt_rot, ctx_gt_trans,
        model_points, Arow, Bcol, pw, out, B, N);

    dim3 grid(N / (CW * 32), B, 2);   // (16, 8, 2) = 256 blocks
    k_mfma<<<grid, CW * 64, 0, stream>>>(Arow, Bcol, pw, out, B, N);
}